// Round 2
// baseline (253.264 us; speedup 1.0000x reference)
//
#include <hip/hip_runtime.h>

// ---------------- problem constants ----------------
#define BATCH 2
#define NQ    4096        // em1 rows per batch
#define MK    4096        // em2 rows per batch
#define DD    256         // head dim
#define ODIM  512         // fc out
#define SDIM  512         // fc in (2*DD)

#define BM     64         // q rows per flash block
#define BK     64         // keys per inner tile
#define MSPLIT 4
#define MCHUNK (MK / MSPLIT)   // 1024

typedef short bf16x8 __attribute__((ext_vector_type(8)));   // 8 bf16 in 4 VGPRs
typedef float f32x16 __attribute__((ext_vector_type(16)));

__device__ __forceinline__ float bf2f(unsigned short h) {
    unsigned int u = ((unsigned int)h) << 16;
    float f;
    __builtin_memcpy(&f, &u, 4);
    return f;
}
__device__ __forceinline__ unsigned short f2bf(float f) {
    unsigned int u;
    __builtin_memcpy(&u, &f, 4);
    u = (u + 0x7FFFu + ((u >> 16) & 1u)) >> 16;   // RNE
    return (unsigned short)u;
}
union frag_cast { uint4 u; bf16x8 b; unsigned short h[8]; };
__device__ __forceinline__ bf16x8 ldg_frag(const unsigned short* p) {
    frag_cast c;
    c.u = *(const uint4*)p;
    return c.b;
}

// ---------------- kernel 0: zero fp32 accumulators ----------------
__global__ void zero_kernel(float4* p, int n4) {
    int i = blockIdx.x * 256 + threadIdx.x;
    if (i < n4) p[i] = make_float4(0.f, 0.f, 0.f, 0.f);
}

// ---------------- kernel 0b: convert em1 (f32) and W (f32) to bf16 copies -----
__global__ void cvt_kernel(const float* em1, const float* W,
                           unsigned short* e1b, unsigned short* wb,
                           int n1, int ntot) {
    int e = (blockIdx.x * 256 + threadIdx.x) * 4;
    if (e >= ntot) return;
    const float* src;
    unsigned short* dst;
    if (e < n1) { src = em1 + e; dst = e1b + e; }
    else        { src = W + (e - n1); dst = wb + (e - n1); }
    float4 v = *(const float4*)src;
    ushort4 o;
    o.x = f2bf(v.x); o.y = f2bf(v.y); o.z = f2bf(v.z); o.w = f2bf(v.w);
    *(ushort4*)dst = o;
}

// ---------------- kernel 1: L2-normalize rows (one wave per row), f32 -> bf16 -
__global__ void norm_kernel(const float* em1, const float* em2,
                            unsigned short* qn, unsigned short* kn) {
    int row  = blockIdx.x * 4 + (threadIdx.x >> 6);   // 0..16383
    int lane = threadIdx.x & 63;
    const float* src;
    unsigned short* dst;
    if (row < BATCH * NQ) {
        src = em1 + (size_t)row * DD;
        dst = qn  + (size_t)row * DD;
    } else {
        int r = row - BATCH * NQ;
        src = em2 + (size_t)r * DD;
        dst = kn  + (size_t)r * DD;
    }
    float4 v = *(const float4*)(src + lane * 4);
    float ss = v.x * v.x + v.y * v.y + v.z * v.z + v.w * v.w;
#pragma unroll
    for (int off = 1; off < 64; off <<= 1) ss += __shfl_xor(ss, off, 64);
    float rn = rsqrtf(fmaxf(ss, 1e-6f));
    ushort4 o;
    o.x = f2bf(v.x * rn); o.y = f2bf(v.y * rn);
    o.z = f2bf(v.z * rn); o.w = f2bf(v.w * rn);
    *(ushort4*)(dst + lane * 4) = o;
}

// ---------------- kernel 2: transpose em2 (f32) -> vt bf16 [B][D][M] ----------
__global__ void transpose_kernel(const float* em2, unsigned short* vt) {
    __shared__ unsigned short T[64 * 68];
    int tid   = threadIdx.x;
    int bid   = blockIdx.x;
    int batch = bid >> 8;         // 256 tiles per batch
    int t2    = bid & 255;
    int mt = t2 >> 2, dt = t2 & 3;
    int m0 = mt * 64, d0 = dt * 64;
    const float* base = em2 + (size_t)batch * MK * DD;
#pragma unroll
    for (int it = 0; it < 4; it++) {
        int key = it * 16 + (tid >> 4);
        int dim = (tid & 15) * 4;
        float4 v = *(const float4*)(base + (size_t)(m0 + key) * DD + d0 + dim);
        ushort4 o;
        o.x = f2bf(v.x); o.y = f2bf(v.y); o.z = f2bf(v.z); o.w = f2bf(v.w);
        *(ushort4*)&T[key * 68 + dim] = o;
    }
    __syncthreads();
    unsigned short* obase = vt + (size_t)batch * DD * MK;
#pragma unroll
    for (int it = 0; it < 4; it++) {
        int dim  = it * 16 + (tid >> 4);
        int key4 = (tid & 15) * 4;
        ushort4 o;
        o.x = T[(key4 + 0) * 68 + dim];
        o.y = T[(key4 + 1) * 68 + dim];
        o.z = T[(key4 + 2) * 68 + dim];
        o.w = T[(key4 + 3) * 68 + dim];
        *(ushort4*)(obase + (size_t)(d0 + dim) * MK + m0 + key4) = o;
    }
}

// ---------------- kernel 3: flash attention (no-max softmax: s in [-1,1]) ------
// grid = 512 blocks (128 row-blocks x 4 key-chunks), 256 threads (4 waves)
// wave w: S-tile rows 32*(w>>1), cols 32*(w&1); X-tile rows 32*(w>>1), dims 128*(w&1)
__global__ __launch_bounds__(256, 2)
void flash_kernel(const unsigned short* qn, const unsigned short* kn,
                  const unsigned short* vt, float* Xbuf, float* lbuf) {
    __shared__ unsigned short P[BM * 72];   // padded stride 72 keeps 16B-aligned b128 reads
    int tid   = threadIdx.x;
    int lane  = tid & 63;
    int w     = tid >> 6;
    int l31   = lane & 31;
    int lhalf = lane >> 5;
    int bid    = blockIdx.x;
    int mchunk = bid & 3;
    int rowblk = bid >> 2;            // 0..127
    int batch  = rowblk >> 6;         // 64 row-blocks per batch
    int r0     = rowblk * BM;         // global row in [0, 8192)
    int keyrow0 = batch * MK + mchunk * MCHUNK;   // row base into kn
    size_t vbase = (size_t)batch * DD * MK;

    int mrow_off = 32 * (w >> 1);
    int ncol_off = 32 * (w & 1);

    // preload Q A-frags for this wave's 32 rows: A[m=l31][k = kk*16 + lhalf*8 + j]
    bf16x8 qf[16];
    {
        const unsigned short* qrow =
            qn + (size_t)(r0 + mrow_off + l31) * DD + lhalf * 8;
#pragma unroll
        for (int kk = 0; kk < 16; kk++) qf[kk] = ldg_frag(qrow + kk * 16);
    }

    f32x16 xacc[4];
#pragma unroll
    for (int t = 0; t < 4; t++)
#pragma unroll
        for (int i = 0; i < 16; i++) xacc[t][i] = 0.f;
    float lpart[16];
#pragma unroll
    for (int i = 0; i < 16; i++) lpart[i] = 0.f;

    for (int kt = 0; kt < MCHUNK / BK; kt++) {   // 16 key-tiles
        // ---- QK^T: S-tile 32x32, K over D=256 ----
        f32x16 sacc;
#pragma unroll
        for (int i = 0; i < 16; i++) sacc[i] = 0.f;
        const unsigned short* krow =
            kn + (size_t)(keyrow0 + kt * BK + ncol_off + l31) * DD + lhalf * 8;
#pragma unroll
        for (int kk = 0; kk < 16; kk++) {
            bf16x8 bf = ldg_frag(krow + kk * 16);
            sacc = __builtin_amdgcn_mfma_f32_32x32x16_bf16(qf[kk], bf, sacc, 0, 0, 0);
        }
        __syncthreads();   // previous iteration's P reads complete
        // ---- P = exp(s-1) (cosine => max==1, no rescale needed), C-layout -> LDS
#pragma unroll
        for (int i = 0; i < 16; i++) {
            float p = __expf(sacc[i] - 1.0f);
            unsigned short pb = f2bf(p);
            lpart[i] += bf2f(pb);   // denominator from the SAME quantized weights
            int m = mrow_off + (i & 3) + 8 * (i >> 2) + 4 * lhalf;
            P[m * 72 + ncol_off + l31] = pb;
        }
        __syncthreads();
        // ---- PV: X[m][dim] += P[m][key] * V[key][dim], B-frags from vt (contig)
        const unsigned short* vtile =
            vt + vbase + (size_t)(mchunk * MCHUNK + kt * BK) + lhalf * 8;
#pragma unroll
        for (int ks = 0; ks < 4; ks++) {
            frag_cast ac;
            ac.u = *(const uint4*)&P[(mrow_off + l31) * 72 + ks * 16 + lhalf * 8];
#pragma unroll
            for (int nt = 0; nt < 4; nt++) {
                int dcol = 128 * (w & 1) + nt * 32 + l31;
                bf16x8 bf = ldg_frag(vtile + (size_t)dcol * MK + ks * 16);
                xacc[nt] = __builtin_amdgcn_mfma_f32_32x32x16_bf16(ac.b, bf, xacc[nt], 0, 0, 0);
            }
        }
    }

    // ---- reduce l over the 32 key-columns of this wave's S-tile, add to lbuf
#pragma unroll
    for (int i = 0; i < 16; i++) {
        float v = lpart[i];
#pragma unroll
        for (int off = 1; off < 32; off <<= 1) v += __shfl_xor(v, off, 64);
        if (l31 == 0) {
            int m = mrow_off + (i & 3) + 8 * (i >> 2) + 4 * lhalf;
            atomicAdd(&lbuf[r0 + m], v);
        }
    }
    // ---- accumulate partial X (fp32)
#pragma unroll
    for (int nt = 0; nt < 4; nt++) {
        int dcol = 128 * (w & 1) + nt * 32 + l31;
#pragma unroll
        for (int i = 0; i < 16; i++) {
            int m = mrow_off + (i & 3) + 8 * (i >> 2) + 4 * lhalf;
            atomicAdd(&Xbuf[(size_t)(r0 + m) * DD + dcol], xacc[nt][i]);
        }
    }
}

// ---------------- kernel 4: h = relu([em1, X/l] @ W^T + b), f32 out -----------
// grid = 256 blocks (64 row-blocks x 4 col-blocks), 256 threads (4 waves)
// wave: 64 rows x 64 cols -> 2x2 tiles of 32x32
__global__ __launch_bounds__(256, 2)
void final_gemm(const unsigned short* e1b, const float* Xbuf, const float* lbuf,
                const unsigned short* wb, const float* bias,
                float* out) {
    int tid   = threadIdx.x;
    int lane  = tid & 63;
    int w     = tid >> 6;
    int l31   = lane & 31;
    int lhalf = lane >> 5;
    int bid = blockIdx.x;
    int cb = bid & 3;
    int rb = bid >> 2;
    int R0 = rb * 128 + 64 * (w & 1);
    int C0 = cb * 128 + 64 * (w >> 1);

    f32x16 acc[2][2];
#pragma unroll
    for (int a = 0; a < 2; a++)
#pragma unroll
        for (int b2 = 0; b2 < 2; b2++)
#pragma unroll
            for (int i = 0; i < 16; i++) acc[a][b2][i] = 0.f;

    int   rA[2];
    float rinv[2];
#pragma unroll
    for (int mt = 0; mt < 2; mt++) {
        rA[mt]   = R0 + mt * 32 + l31;
        rinv[mt] = 1.0f / lbuf[rA[mt]];
    }

    for (int kk = 0; kk < 32; kk++) {   // K = 512, steps of 16
        int k0 = kk * 16 + lhalf * 8;
        bf16x8 afr[2];
        if (kk < 16) {
            // emb[:, 0:256] = em1 (raw, pre-converted bf16)
#pragma unroll
            for (int mt = 0; mt < 2; mt++)
                afr[mt] = ldg_frag(e1b + (size_t)rA[mt] * DD + k0);
        } else {
            // emb[:, 256:512] = X / l  (fp32 -> bf16)
#pragma unroll
            for (int mt = 0; mt < 2; mt++) {
                const float* xp = Xbuf + (size_t)rA[mt] * DD + (k0 - 256);
                float4 a = *(const float4*)xp;
                float4 c = *(const float4*)(xp + 4);
                frag_cast u;
                u.h[0] = f2bf(a.x * rinv[mt]); u.h[1] = f2bf(a.y * rinv[mt]);
                u.h[2] = f2bf(a.z * rinv[mt]); u.h[3] = f2bf(a.w * rinv[mt]);
                u.h[4] = f2bf(c.x * rinv[mt]); u.h[5] = f2bf(c.y * rinv[mt]);
                u.h[6] = f2bf(c.z * rinv[mt]); u.h[7] = f2bf(c.w * rinv[mt]);
                afr[mt] = u.b;
            }
        }
        bf16x8 bfr[2];
#pragma unroll
        for (int nt = 0; nt < 2; nt++)
            bfr[nt] = ldg_frag(wb + (size_t)(C0 + nt * 32 + l31) * SDIM + k0);
#pragma unroll
        for (int mt = 0; mt < 2; mt++)
#pragma unroll
            for (int nt = 0; nt < 2; nt++)
                acc[mt][nt] = __builtin_amdgcn_mfma_f32_32x32x16_bf16(
                    afr[mt], bfr[nt], acc[mt][nt], 0, 0, 0);
    }

#pragma unroll
    for (int nt = 0; nt < 2; nt++) {
        int col = C0 + nt * 32 + l31;
        float bb = bias[col];
#pragma unroll
        for (int mt = 0; mt < 2; mt++) {
#pragma unroll
            for (int i = 0; i < 16; i++) {
                int row = R0 + mt * 32 + (i & 3) + 8 * (i >> 2) + 4 * lhalf;
                float v = acc[mt][nt][i] + bb;
                v = v > 0.f ? v : 0.f;
                out[(size_t)row * ODIM + col] = v;
            }
        }
    }
}

// ---------------- launch ----------------
extern "C" void kernel_launch(void* const* d_in, const int* in_sizes, int n_in,
                              void* d_out, int out_size, void* d_ws, size_t ws_size,
                              hipStream_t stream) {
    const float* em1  = (const float*)d_in[0];
    const float* em2  = (const float*)d_in[1];
    const float* W    = (const float*)d_in[2];
    const float* bias = (const float*)d_in[3];
    float* out = (float*)d_out;

    char* ws = (char*)d_ws;
    unsigned short* qn  = (unsigned short*)ws;                      // 4 MB
    unsigned short* kn  = qn + (size_t)BATCH * NQ * DD;             // 4 MB
    unsigned short* vt  = kn + (size_t)BATCH * MK * DD;             // 4 MB
    unsigned short* e1b = vt + (size_t)BATCH * DD * MK;             // 4 MB
    unsigned short* wb  = e1b + (size_t)BATCH * NQ * DD;            // 0.5 MB
    float* Xbuf = (float*)(ws + 17ull * 1024 * 1024);               // 8 MB
    float* lbuf = Xbuf + (size_t)BATCH * NQ * DD;                   // 32 KB

    const int nzero4 = (BATCH * NQ * DD + BATCH * NQ) / 4;          // 526336
    zero_kernel<<<(nzero4 + 255) / 256, 256, 0, stream>>>((float4*)Xbuf, nzero4);

    const int n1   = BATCH * NQ * DD;           // em1 elements
    const int ntot = n1 + ODIM * SDIM;          // + W elements
    cvt_kernel<<<(ntot / 4 + 255) / 256, 256, 0, stream>>>(em1, W, e1b, wb, n1, ntot);

    norm_kernel<<<(BATCH * (NQ + MK)) / 4, 256, 0, stream>>>(em1, em2, qn, kn);
    transpose_kernel<<<BATCH * (MK / 64) * (DD / 64), 256, 0, stream>>>(em2, vt);
    flash_kernel<<<(BATCH * NQ / BM) * MSPLIT, 256, 0, stream>>>(qn, kn, vt, Xbuf, lbuf);
    final_gemm<<<(BATCH * NQ / 128) * (ODIM / 128), 256, 0, stream>>>(
        e1b, Xbuf, lbuf, wb, bias, out);
}